// Round 1
// baseline (32.410 us; speedup 1.0000x reference)
//
#include <hip/hip_runtime.h>
#include <hip/hip_bf16.h>

#define DT_STEP 0.01f

// x: (B*S*N, 6) flattened samples. Per sample, gradient of energy wrt x only
// involves the blade-0 slice of every intermediate (see analysis).
__global__ __launch_bounds__(256) void hvnn_kernel(
    const float* __restrict__ x,      // (NS, 6)
    const float* __restrict__ W_in,   // (6, 256)
    const float* __restrict__ b_in,   // (256)
    const float* __restrict__ W1,     // (32, 8)
    const float* __restrict__ b1,     // (32, 32)
    const float* __restrict__ W2,     // (32, 32)
    const float* __restrict__ b2,     // (32, 32)
    const float* __restrict__ W3,     // (1, 32) -> (32)
    float* __restrict__ out,          // (NS, 6)
    int NS)
{
    __shared__ float sWin[6][8];   // W_in[d][i*32]
    __shared__ float sBin[8];      // b_in[i*32]
    __shared__ float sW1[32][8];   // W1[o][i]
    __shared__ float sB1[32];      // b1[o][0]
    __shared__ float sW2[32][32];  // W2[o][i]
    __shared__ float sB2[32];      // b2[o][0]
    __shared__ float sW3[32];      // W3[0][i]

    const int tid = threadIdx.x;
    if (tid < 48) sWin[tid / 8][tid % 8] = W_in[(tid / 8) * 256 + (tid % 8) * 32];
    if (tid < 8)  sBin[tid] = b_in[tid * 32];
    { int o = tid >> 3, i = tid & 7; sW1[o][i] = W1[o * 8 + i]; }  // 256 threads = 32x8
    if (tid < 32) sB1[tid] = b1[tid * 32];
    for (int j = tid; j < 1024; j += 256) sW2[j >> 5][j & 31] = W2[j];
    if (tid < 32) sB2[tid] = b2[tid * 32];
    if (tid < 32) sW3[tid] = W3[tid];
    __syncthreads();

    const int s = blockIdx.x * 256 + tid;
    if (s >= NS) return;

    // load sample (6 floats, stride-24B; small traffic, fine)
    float xv[6];
    const float* xp = x + (size_t)s * 6;
#pragma unroll
    for (int d = 0; d < 6; ++d) xv[d] = xp[d];

    // ---- forward (blade-0 slice only) ----
    float h0[8];
#pragma unroll
    for (int i = 0; i < 8; ++i) {
        float a = sBin[i];
#pragma unroll
        for (int d = 0; d < 6; ++d) a = fmaf(xv[d], sWin[d][i], a);
        h0[i] = a;
    }

    float h1p[32], g1[32], h1[32];
#pragma unroll
    for (int o = 0; o < 32; ++o) {
        float a = sB1[o];
#pragma unroll
        for (int i = 0; i < 8; ++i) a = fmaf(h0[i], sW1[o][i], a);
        h1p[o] = a;
        float g = 1.0f / (1.0f + __expf(-a));
        g1[o] = g;
        h1[o] = a * g;
    }

    // layer2 pre-act + fused backward-through-act2: d2[o] = dE/dh2_pre[o][0]
    float d2[32];
#pragma unroll
    for (int o = 0; o < 32; ++o) {
        float a = sB2[o];
#pragma unroll
        for (int i = 0; i < 32; ++i) a = fmaf(h1[i], sW2[o][i], a);
        float g = 1.0f / (1.0f + __expf(-a));
        d2[o] = sW3[o] * g * (1.0f + a * (1.0f - g));
    }

    // ---- backward ----
    // u1[i] = sum_o d2[o]*W2[o][i]; d1 = through act1
    float d1[32];
#pragma unroll
    for (int o = 0; o < 32; ++o) {
        float u = 0.0f;
#pragma unroll
        for (int j = 0; j < 32; ++j) u = fmaf(d2[j], sW2[j][o], u);
        d1[o] = u * g1[o] * (1.0f + h1p[o] * (1.0f - g1[o]));
    }

    float v[8];
#pragma unroll
    for (int i = 0; i < 8; ++i) {
        float a = 0.0f;
#pragma unroll
        for (int o = 0; o < 32; ++o) a = fmaf(d1[o], sW1[o][i], a);
        v[i] = a;
    }

    float gx[6];
#pragma unroll
    for (int d = 0; d < 6; ++d) {
        float a = 0.0f;
#pragma unroll
        for (int i = 0; i < 8; ++i) a = fmaf(v[i], sWin[d][i], a);
        gx[d] = a;
    }

    // next_state: q += DT*grad_p ; p -= DT*grad_q
    float* op = out + (size_t)s * 6;
    op[0] = xv[0] + DT_STEP * gx[3];
    op[1] = xv[1] + DT_STEP * gx[4];
    op[2] = xv[2] + DT_STEP * gx[5];
    op[3] = xv[3] - DT_STEP * gx[0];
    op[4] = xv[4] - DT_STEP * gx[1];
    op[5] = xv[5] - DT_STEP * gx[2];
}

extern "C" void kernel_launch(void* const* d_in, const int* in_sizes, int n_in,
                              void* d_out, int out_size, void* d_ws, size_t ws_size,
                              hipStream_t stream) {
    const float* x    = (const float*)d_in[0];
    const float* W_in = (const float*)d_in[1];
    const float* b_in = (const float*)d_in[2];
    const float* W1   = (const float*)d_in[3];
    const float* b1   = (const float*)d_in[4];
    const float* W2   = (const float*)d_in[5];
    const float* b2   = (const float*)d_in[6];
    const float* W3   = (const float*)d_in[7];
    float* out = (float*)d_out;

    const int NS = in_sizes[0] / 6;  // B*S*N samples
    const int blocks = (NS + 255) / 256;
    hvnn_kernel<<<blocks, 256, 0, stream>>>(x, W_in, b_in, W1, b1, W2, b2, W3, out, NS);
}

// Round 2
// 23.668 us; speedup vs baseline: 1.3693x; 1.3693x over previous
//
#include <hip/hip_runtime.h>
#include <hip/hip_bf16.h>

#define DT_STEP 0.01f

// One thread per (bs,n) sample. All weight accesses are wave-uniform ->
// compiler emits s_load (scalar cache, SMEM pipe), FMAs consume SGPRs
// directly. No LDS at all. Backward matvecs are row-axpy so every weight
// access is a contiguous row (s_load_dwordx8/x16 friendly); layer-2 fwd
// and bwd share each W2 row load.
__global__ __launch_bounds__(256) void hvnn_kernel(
    const float* __restrict__ x,      // (NS, 6)
    const float* __restrict__ W_in,   // (6, 256)
    const float* __restrict__ b_in,   // (256)
    const float* __restrict__ W1,     // (32, 8)
    const float* __restrict__ b1,     // (32, 32)
    const float* __restrict__ W2,     // (32, 32)
    const float* __restrict__ b2,     // (32, 32)
    const float* __restrict__ W3,     // (32)
    float* __restrict__ out,          // (NS, 6)
    int NS)
{
    const int s = blockIdx.x * 256 + threadIdx.x;
    if (s >= NS) return;

    // load sample as 3x float2 (8B aligned: s*24 % 8 == 0)
    const float2* xp2 = reinterpret_cast<const float2*>(x + (size_t)s * 6);
    float2 xa = xp2[0], xb = xp2[1], xc = xp2[2];
    float xv[6] = {xa.x, xa.y, xb.x, xb.y, xc.x, xc.y};

    // ---- embed (blade-0 slice): h0[i] = sum_d xv[d]*W_in[d][i*32] + b_in[i*32]
    float h0[8];
#pragma unroll
    for (int i = 0; i < 8; ++i) {
        float a = b_in[i * 32];
#pragma unroll
        for (int d = 0; d < 6; ++d) a = fmaf(xv[d], W_in[d * 256 + i * 32], a);
        h0[i] = a;
    }

    // ---- layer 1 forward: h1p = W1 @ h0 + b1[:,0]; h1 = h1p*sigmoid(h1p)
    // keep h1 and t1 = g*(1 + h1p*(1-g))  (the act-backward factor)
    float h1[32], t1[32];
#pragma unroll
    for (int o = 0; o < 32; ++o) {
        const float* w1r = W1 + o * 8;   // contiguous row, uniform -> s_load
        float a = b1[o * 32];
#pragma unroll
        for (int i = 0; i < 8; ++i) a = fmaf(h0[i], w1r[i], a);
        float g = 1.0f / (1.0f + __expf(-a));
        h1[o] = a * g;
        t1[o] = g * fmaf(a, 1.0f - g, 1.0f);
    }

    // ---- layer 2 forward + backward fused per row:
    // a = W2[j]·h1 + b2[j,0]; d2 = W3[j]*g*(1+a*(1-g)); u1 += d2*W2[j]
    float u1[32];
#pragma unroll
    for (int i = 0; i < 32; ++i) u1[i] = 0.0f;
#pragma unroll
    for (int j = 0; j < 32; ++j) {
        const float* w2r = W2 + j * 32;  // contiguous row, loaded once (fwd+bwd)
        float a = b2[j * 32];
#pragma unroll
        for (int i = 0; i < 32; ++i) a = fmaf(h1[i], w2r[i], a);
        float g = 1.0f / (1.0f + __expf(-a));
        float d2 = W3[j] * g * fmaf(a, 1.0f - g, 1.0f);
#pragma unroll
        for (int i = 0; i < 32; ++i) u1[i] = fmaf(d2, w2r[i], u1[i]);
    }

    // ---- layer 1 backward: d1[o] = u1[o]*t1[o]; v += d1[o]*W1[o] (row axpy)
    float v[8];
#pragma unroll
    for (int i = 0; i < 8; ++i) v[i] = 0.0f;
#pragma unroll
    for (int o = 0; o < 32; ++o) {
        const float* w1r = W1 + o * 8;
        float d1 = u1[o] * t1[o];
#pragma unroll
        for (int i = 0; i < 8; ++i) v[i] = fmaf(d1, w1r[i], v[i]);
    }

    // ---- embed backward: gx[d] = sum_i v[i]*W_in[d][i*32]
    float gx[6];
#pragma unroll
    for (int d = 0; d < 6; ++d) {
        float a = 0.0f;
#pragma unroll
        for (int i = 0; i < 8; ++i) a = fmaf(v[i], W_in[d * 256 + i * 32], a);
        gx[d] = a;
    }

    // next_state: q += DT*grad_p ; p -= DT*grad_q   (3x float2 store)
    float2* op2 = reinterpret_cast<float2*>(out + (size_t)s * 6);
    op2[0] = make_float2(fmaf(DT_STEP, gx[3], xv[0]), fmaf(DT_STEP, gx[4], xv[1]));
    op2[1] = make_float2(fmaf(DT_STEP, gx[5], xv[2]), fmaf(-DT_STEP, gx[0], xv[3]));
    op2[2] = make_float2(fmaf(-DT_STEP, gx[1], xv[4]), fmaf(-DT_STEP, gx[2], xv[5]));
}

extern "C" void kernel_launch(void* const* d_in, const int* in_sizes, int n_in,
                              void* d_out, int out_size, void* d_ws, size_t ws_size,
                              hipStream_t stream) {
    const float* x    = (const float*)d_in[0];
    const float* W_in = (const float*)d_in[1];
    const float* b_in = (const float*)d_in[2];
    const float* W1   = (const float*)d_in[3];
    const float* b1   = (const float*)d_in[4];
    const float* W2   = (const float*)d_in[5];
    const float* b2   = (const float*)d_in[6];
    const float* W3   = (const float*)d_in[7];
    float* out = (float*)d_out;

    const int NS = in_sizes[0] / 6;  // B*S*N samples
    const int blocks = (NS + 255) / 256;
    hvnn_kernel<<<blocks, 256, 0, stream>>>(x, W_in, b_in, W1, b1, W2, b2, W3, out, NS);
}

// Round 3
// 22.875 us; speedup vs baseline: 1.4168x; 1.0347x over previous
//
#include <hip/hip_runtime.h>
#include <hip/hip_bf16.h>

#define DT_STEP 0.01f

typedef __bf16 bf16x8 __attribute__((ext_vector_type(8)));
typedef float  f32x4  __attribute__((ext_vector_type(4)));

// ---------------------------------------------------------------------------
// Setup kernel: fold constant weight algebra into d_ws (480 floats).
//   We[d][o]  (6x32) = sum_i Win[d][i*32] * W1[o][i]          (wsf[0..192))
//   be[o]     (32)   = b1[o*32] + sum_i bin[i*32]*W1[o][i]    (wsf[192..224))
//   Wcp[o][d] (32x8 padded, d<6 real) = sign * Wc[o][dd]      (wsf[224..480))
//     Wc[o][d'] = sum_i W1[o][i]*Win[d'][i*32]
//     dd = d<3 ? d+3 : d-3 ; sign = d<3 ? +1 : -1   (Hamiltonian swap folded)
// ---------------------------------------------------------------------------
__global__ void hvnn_setup(const float* __restrict__ Win, const float* __restrict__ bin,
                           const float* __restrict__ W1,  const float* __restrict__ b1,
                           float* __restrict__ wsf)
{
    const int tid = threadIdx.x;  // 256 threads, 1 block
    if (tid < 192) {
        int d = tid >> 5, o = tid & 31;
        float a = 0.f;
#pragma unroll
        for (int i = 0; i < 8; ++i) a = fmaf(Win[d * 256 + i * 32], W1[o * 8 + i], a);
        wsf[d * 32 + o] = a;
    }
    if (tid < 32) {
        float a = b1[tid * 32];
#pragma unroll
        for (int i = 0; i < 8; ++i) a = fmaf(bin[i * 32], W1[tid * 8 + i], a);
        wsf[192 + tid] = a;
    }
    {
        int o = tid >> 3, d = tid & 7;
        float v = 0.f;
        if (d < 6) {
            int dd = d < 3 ? d + 3 : d - 3;
            float sg = d < 3 ? 1.f : -1.f;
            float a = 0.f;
#pragma unroll
            for (int i = 0; i < 8; ++i) a = fmaf(W1[o * 8 + i], Win[dd * 256 + i * 32], a);
            v = sg * a;
        }
        wsf[224 + o * 8 + d] = v;
    }
}

// ---------------------------------------------------------------------------
// Main kernel: one wave per 16-sample tile. All weights live in B-fragments
// (loaded once). Chain (7 MFMAs): h1p = x@We+be -> act -> h2p = h1@W2T+b2
// -> d2 -> u1 = d2@W2 -> d1 = u1*t1 -> gxp = d1@Wcp -> out = x + DT*gxp.
// C-layout (col=lane&15, row=(lane>>4)*4+e) -> A-layout (row=lane&15,
// k=(lane>>4)*8+j) transposes via per-wave LDS, bf16, XOR-swizzled.
// ---------------------------------------------------------------------------
__global__ __launch_bounds__(256) void hvnn_mfma(
    const float* __restrict__ x,   // (NS,6)
    const float* __restrict__ W2,  // (32,32)
    const float* __restrict__ b2,  // (32,32)
    const float* __restrict__ W3,  // (32)
    const float* __restrict__ wsf, // setup output
    float* __restrict__ out,       // (NS,6)
    int ntiles)
{
    __shared__ __align__(16) char ldsbuf[4][3][1024];

    const int lane = threadIdx.x & 63;
    const int wv   = threadIdx.x >> 6;
    const int tile = blockIdx.x * 4 + wv;
    if (tile >= ntiles) return;
    const int l15 = lane & 15, lhi = lane >> 4;

    const float* We  = wsf;        // [6][32]
    const float* be  = wsf + 192;  // [32]
    const float* Wcp = wsf + 224;  // [32][8]

    // ---- A-fragment: x tile (lanes 0-15 carry sample=lane, k=d<6) ----
    bf16x8 ax = {};
    if (lane < 16) {
        const float* xp = x + (size_t)(tile * 16 + lane) * 6;
#pragma unroll
        for (int d = 0; d < 6; ++d) ax[d] = (__bf16)xp[d];
    }

    // ---- B-fragments (once per wave) ----
    bf16x8 bwe0 = {}, bwe1 = {};
    if (lane < 16) {
#pragma unroll
        for (int d = 0; d < 6; ++d) {
            bwe0[d] = (__bf16)We[d * 32 + l15];
            bwe1[d] = (__bf16)We[d * 32 + l15 + 16];
        }
    }
    bf16x8 bw2t0, bw2t1;  // forward: B(k=i, n=j) = W2[j][i]
    {
        const float* p0 = W2 + l15 * 32 + lhi * 8;
        const float* p1 = W2 + (l15 + 16) * 32 + lhi * 8;
#pragma unroll
        for (int j = 0; j < 8; ++j) { bw2t0[j] = (__bf16)p0[j]; bw2t1[j] = (__bf16)p1[j]; }
    }
    bf16x8 bw2b0, bw2b1;  // backward: B(k=j, n=i) = W2[j][i]
    {
        const float* q0 = W2 + (lhi * 8) * 32 + l15;
        const float* q1 = q0 + 16;
#pragma unroll
        for (int j = 0; j < 8; ++j) { bw2b0[j] = (__bf16)q0[j * 32]; bw2b1[j] = (__bf16)q1[j * 32]; }
    }
    bf16x8 bwc = {};      // output: B(k=o, n=d<6) = Wcp[o][d]
    if (l15 < 6) {
        const float* p = Wcp + (lhi * 8) * 8 + l15;
#pragma unroll
        for (int j = 0; j < 8; ++j) bwc[j] = (__bf16)p[j * 8];
    }
    const float be0  = be[l15], be1 = be[l15 + 16];
    const float b2c0 = b2[l15 * 32], b2c1 = b2[(l15 + 16) * 32];
    const float w3c0 = W3[l15], w3c1 = W3[l15 + 16];

    char* buf0 = &ldsbuf[wv][0][0];
    char* buf1 = &ldsbuf[wv][1][0];
    char* buf2 = &ldsbuf[wv][2][0];

    // ---- layer 1: h1p = x @ We + be ----
    f32x4 c0 = {be0, be0, be0, be0};
    f32x4 c1 = {be1, be1, be1, be1};
    f32x4 h1p0 = __builtin_amdgcn_mfma_f32_16x16x32_bf16(ax, bwe0, c0, 0, 0, 0);
    f32x4 h1p1 = __builtin_amdgcn_mfma_f32_16x16x32_bf16(ax, bwe1, c1, 0, 0, 0);

    // act: h1 = a*sig(a) -> LDS (T1); keep t1 = g*(1+a*(1-g))
    float t10[4], t11[4];
#pragma unroll
    for (int e = 0; e < 4; ++e) {
        int s = lhi * 4 + e;
        int m = (s & 7) << 4;
        {
            float a = h1p0[e];
            float g = 1.f / (1.f + __expf(-a));
            t10[e] = g * fmaf(a, 1.f - g, 1.f);
            *(__bf16*)(buf0 + ((s * 64 + l15 * 2) ^ m)) = (__bf16)(a * g);
        }
        {
            float a = h1p1[e];
            float g = 1.f / (1.f + __expf(-a));
            t11[e] = g * fmaf(a, 1.f - g, 1.f);
            *(__bf16*)(buf0 + ((s * 64 + (l15 + 16) * 2) ^ m)) = (__bf16)(a * g);
        }
    }
    bf16x8 h1a = *(const bf16x8*)(buf0 + ((l15 * 64 + lhi * 16) ^ ((l15 & 7) << 4)));

    // ---- layer 2 fwd: h2p = h1 @ W2^T + b2 ; d2 = W3*g*(1+a*(1-g)) ----
    f32x4 cb0 = {b2c0, b2c0, b2c0, b2c0};
    f32x4 cb1 = {b2c1, b2c1, b2c1, b2c1};
    f32x4 h2p0 = __builtin_amdgcn_mfma_f32_16x16x32_bf16(h1a, bw2t0, cb0, 0, 0, 0);
    f32x4 h2p1 = __builtin_amdgcn_mfma_f32_16x16x32_bf16(h1a, bw2t1, cb1, 0, 0, 0);
#pragma unroll
    for (int e = 0; e < 4; ++e) {
        int s = lhi * 4 + e;
        int m = (s & 7) << 4;
        {
            float a = h2p0[e];
            float g = 1.f / (1.f + __expf(-a));
            *(__bf16*)(buf1 + ((s * 64 + l15 * 2) ^ m)) = (__bf16)(w3c0 * g * fmaf(a, 1.f - g, 1.f));
        }
        {
            float a = h2p1[e];
            float g = 1.f / (1.f + __expf(-a));
            *(__bf16*)(buf1 + ((s * 64 + (l15 + 16) * 2) ^ m)) = (__bf16)(w3c1 * g * fmaf(a, 1.f - g, 1.f));
        }
    }
    bf16x8 d2a = *(const bf16x8*)(buf1 + ((l15 * 64 + lhi * 16) ^ ((l15 & 7) << 4)));

    // ---- backward: u1 = d2 @ W2 ; d1 = u1 * t1 ----
    f32x4 z = {0.f, 0.f, 0.f, 0.f};
    f32x4 u10 = __builtin_amdgcn_mfma_f32_16x16x32_bf16(d2a, bw2b0, z, 0, 0, 0);
    f32x4 u11 = __builtin_amdgcn_mfma_f32_16x16x32_bf16(d2a, bw2b1, z, 0, 0, 0);
#pragma unroll
    for (int e = 0; e < 4; ++e) {
        int s = lhi * 4 + e;
        int m = (s & 7) << 4;
        *(__bf16*)(buf2 + ((s * 64 + l15 * 2) ^ m))        = (__bf16)(u10[e] * t10[e]);
        *(__bf16*)(buf2 + ((s * 64 + (l15 + 16) * 2) ^ m)) = (__bf16)(u11[e] * t11[e]);
    }
    bf16x8 d1a = *(const bf16x8*)(buf2 + ((l15 * 64 + lhi * 16) ^ ((l15 & 7) << 4)));

    // ---- output: gxp = d1 @ Wcp (swap+sign folded); out = x + DT*gxp ----
    f32x4 gx = __builtin_amdgcn_mfma_f32_16x16x32_bf16(d1a, bwc, z, 0, 0, 0);

    if (l15 < 6) {
#pragma unroll
        for (int e = 0; e < 4; ++e) {
            size_t idx = (size_t)(tile * 16 + lhi * 4 + e) * 6 + l15;
            out[idx] = fmaf(DT_STEP, gx[e], x[idx]);
        }
    }
}

extern "C" void kernel_launch(void* const* d_in, const int* in_sizes, int n_in,
                              void* d_out, int out_size, void* d_ws, size_t ws_size,
                              hipStream_t stream) {
    const float* x    = (const float*)d_in[0];
    const float* W_in = (const float*)d_in[1];
    const float* b_in = (const float*)d_in[2];
    const float* W1   = (const float*)d_in[3];
    const float* b1   = (const float*)d_in[4];
    const float* W2   = (const float*)d_in[5];
    const float* b2   = (const float*)d_in[6];
    const float* W3   = (const float*)d_in[7];
    float* out = (float*)d_out;
    float* wsf = (float*)d_ws;

    const int NS     = in_sizes[0] / 6;   // 131072 samples
    const int ntiles = NS / 16;           // 8192 (NS divisible by 16)

    hvnn_setup<<<1, 256, 0, stream>>>(W_in, b_in, W1, b1, wsf);
    hvnn_mfma<<<(ntiles + 3) / 4, 256, 0, stream>>>(x, W2, b2, W3, wsf, out, ntiles);
}

// Round 4
// 18.110 us; speedup vs baseline: 1.7896x; 1.2631x over previous
//
#include <hip/hip_runtime.h>
#include <hip/hip_bf16.h>

#define DT_STEP 0.01f

typedef __bf16 bf16x8 __attribute__((ext_vector_type(8)));
typedef float  f32x4  __attribute__((ext_vector_type(4)));

// ---------------------------------------------------------------------------
// Setup: fold weight algebra AND build per-lane MFMA B-fragments into d_ws.
//   We[d][o]  = sum_i Win[d][i*32]*W1[o][i]     (embed folded into layer1)
//   be[o]     = b1[o*32] + sum_i bin[i*32]*W1[o][i]
//   Wcp[o][d] = sign * sum_i W1[o][i]*Win[dd][i*32]   (bwd-embed + Hamiltonian
//               index swap/sign folded; dd = d<3?d+3:d-3, sign = d<3?+1:-1)
// ws layout (bytes): frag k at k*1024 + lane*16 (k=0..6: bwe0,bwe1,bw2t0,
// bw2t1,bw2b0,bw2b1,bwc); per-lane scalars at 7168 + lane*32 (float4 x2).
// ---------------------------------------------------------------------------
__global__ void hvnn_setup(const float* __restrict__ Win, const float* __restrict__ bin,
                           const float* __restrict__ W1,  const float* __restrict__ b1,
                           const float* __restrict__ W2,  const float* __restrict__ b2,
                           const float* __restrict__ W3,  char* __restrict__ ws)
{
    __shared__ float We[6][32];
    __shared__ float be[32];
    __shared__ float Wcp[32][8];
    const int tid = threadIdx.x;  // 256 threads, 1 block
    if (tid < 192) {
        int d = tid >> 5, o = tid & 31;
        float a = 0.f;
#pragma unroll
        for (int i = 0; i < 8; ++i) a = fmaf(Win[d * 256 + i * 32], W1[o * 8 + i], a);
        We[d][o] = a;
    }
    if (tid < 32) {
        float a = b1[tid * 32];
#pragma unroll
        for (int i = 0; i < 8; ++i) a = fmaf(bin[i * 32], W1[tid * 8 + i], a);
        be[tid] = a;
    }
    {
        int o = tid >> 3, d = tid & 7;
        float v = 0.f;
        if (d < 6) {
            int dd = d < 3 ? d + 3 : d - 3;
            float sg = d < 3 ? 1.f : -1.f;
            float a = 0.f;
#pragma unroll
            for (int i = 0; i < 8; ++i) a = fmaf(W1[o * 8 + i], Win[dd * 256 + i * 32], a);
            v = sg * a;
        }
        Wcp[o][d] = v;
    }
    __syncthreads();
    if (tid >= 64) return;
    const int lane = tid, l15 = lane & 15, lhi = lane >> 4;

    bf16x8 f0 = {}, f1 = {}, f2, f3, f4, f5, f6 = {};
    if (lane < 16) {
#pragma unroll
        for (int d = 0; d < 6; ++d) { f0[d] = (__bf16)We[d][l15]; f1[d] = (__bf16)We[d][l15 + 16]; }
    }
#pragma unroll
    for (int j = 0; j < 8; ++j) {
        f2[j] = (__bf16)W2[l15 * 32 + lhi * 8 + j];          // fwd: B(k=i,n=j)=W2[n][k]
        f3[j] = (__bf16)W2[(l15 + 16) * 32 + lhi * 8 + j];
        f4[j] = (__bf16)W2[(lhi * 8 + j) * 32 + l15];        // bwd: B(k=j,n=i)=W2[k][n]
        f5[j] = (__bf16)W2[(lhi * 8 + j) * 32 + l15 + 16];
    }
    if (l15 < 6) {
#pragma unroll
        for (int j = 0; j < 8; ++j) f6[j] = (__bf16)Wcp[lhi * 8 + j][l15];
    }
    ((bf16x8*)(ws + 0 * 1024))[lane] = f0;
    ((bf16x8*)(ws + 1 * 1024))[lane] = f1;
    ((bf16x8*)(ws + 2 * 1024))[lane] = f2;
    ((bf16x8*)(ws + 3 * 1024))[lane] = f3;
    ((bf16x8*)(ws + 4 * 1024))[lane] = f4;
    ((bf16x8*)(ws + 5 * 1024))[lane] = f5;
    ((bf16x8*)(ws + 6 * 1024))[lane] = f6;
    float4 sA = make_float4(be[l15], be[l15 + 16], b2[l15 * 32], b2[(l15 + 16) * 32]);
    float4 sB = make_float4(W3[l15], W3[l15 + 16], 0.f, 0.f);
    ((float4*)(ws + 7168))[lane * 2]     = sA;
    ((float4*)(ws + 7168))[lane * 2 + 1] = sB;
}

// ---------------------------------------------------------------------------
// Main: one wave per 16-sample tile. 11 coalesced VMEM instrs per wave:
// 9 fragment/scalar loads (same addr every wave -> L1) + 1 x load + 1 store.
// x and out staged through per-wave LDS (same-wave DS ops are in-order, no
// barrier needed). Chain: 7 MFMAs + 3 XOR-swizzled LDS transposes.
// ---------------------------------------------------------------------------
__global__ __launch_bounds__(256) void hvnn_mfma(
    const float* __restrict__ x,   // (NS,6)
    const char*  __restrict__ ws,  // fragments from setup
    float* __restrict__ out,       // (NS,6)
    int ntiles)
{
    __shared__ __align__(16) char lds[4][4096];

    const int lane = threadIdx.x & 63;
    const int wv   = threadIdx.x >> 6;
    const int tile = blockIdx.x * 4 + wv;
    if (tile >= ntiles) return;
    const int l15 = lane & 15, lhi = lane >> 4;

    char* buf0 = &lds[wv][0];
    char* buf1 = &lds[wv][1024];
    char* buf2 = &lds[wv][2048];
    char* xbuf = &lds[wv][3072];
    char* obuf = &lds[wv][3584];

    // ---- weights: 7 coalesced 16B fragment loads + 2 scalar-record loads ----
    const bf16x8 bwe0  = ((const bf16x8*)(ws + 0 * 1024))[lane];
    const bf16x8 bwe1  = ((const bf16x8*)(ws + 1 * 1024))[lane];
    const bf16x8 bw2t0 = ((const bf16x8*)(ws + 2 * 1024))[lane];
    const bf16x8 bw2t1 = ((const bf16x8*)(ws + 3 * 1024))[lane];
    const bf16x8 bw2b0 = ((const bf16x8*)(ws + 4 * 1024))[lane];
    const bf16x8 bw2b1 = ((const bf16x8*)(ws + 5 * 1024))[lane];
    const bf16x8 bwc   = ((const bf16x8*)(ws + 6 * 1024))[lane];
    const float4 sA = ((const float4*)(ws + 7168))[lane * 2];
    const float4 sB = ((const float4*)(ws + 7168))[lane * 2 + 1];
    const float be0 = sA.x, be1 = sA.y, b2c0 = sA.z, b2c1 = sA.w;
    const float w3c0 = sB.x, w3c1 = sB.y;

    // ---- x tile: 1 coalesced load -> LDS ----
    if (lane < 48)
        *(float2*)(xbuf + lane * 8) = ((const float2*)x)[(size_t)tile * 48 + lane];

    // A-fragment: lanes 0-15 carry sample=lane, k=d<6
    bf16x8 ax = {};
    if (lane < 16) {
        const float* xr = (const float*)(xbuf + lane * 24);
#pragma unroll
        for (int d = 0; d < 6; ++d) ax[d] = (__bf16)xr[d];
    }

    // ---- layer 1: h1p = x @ We + be ----
    f32x4 c0 = {be0, be0, be0, be0};
    f32x4 c1 = {be1, be1, be1, be1};
    f32x4 h1p0 = __builtin_amdgcn_mfma_f32_16x16x32_bf16(ax, bwe0, c0, 0, 0, 0);
    f32x4 h1p1 = __builtin_amdgcn_mfma_f32_16x16x32_bf16(ax, bwe1, c1, 0, 0, 0);

    // act -> LDS transpose (C layout [sample][chan], XOR-swizzled); keep t1
    float t10[4], t11[4];
#pragma unroll
    for (int e = 0; e < 4; ++e) {
        int s = lhi * 4 + e;
        int m = (s & 7) << 4;
        {
            float a = h1p0[e];
            float g = 1.f / (1.f + __expf(-a));
            t10[e] = g * fmaf(a, 1.f - g, 1.f);
            *(__bf16*)(buf0 + ((s * 64 + l15 * 2) ^ m)) = (__bf16)(a * g);
        }
        {
            float a = h1p1[e];
            float g = 1.f / (1.f + __expf(-a));
            t11[e] = g * fmaf(a, 1.f - g, 1.f);
            *(__bf16*)(buf0 + ((s * 64 + (l15 + 16) * 2) ^ m)) = (__bf16)(a * g);
        }
    }
    bf16x8 h1a = *(const bf16x8*)(buf0 + ((l15 * 64 + lhi * 16) ^ ((l15 & 7) << 4)));

    // ---- layer 2 fwd: h2p = h1 @ W2^T + b2 ; d2 = W3*g*(1+a*(1-g)) ----
    f32x4 cb0 = {b2c0, b2c0, b2c0, b2c0};
    f32x4 cb1 = {b2c1, b2c1, b2c1, b2c1};
    f32x4 h2p0 = __builtin_amdgcn_mfma_f32_16x16x32_bf16(h1a, bw2t0, cb0, 0, 0, 0);
    f32x4 h2p1 = __builtin_amdgcn_mfma_f32_16x16x32_bf16(h1a, bw2t1, cb1, 0, 0, 0);
#pragma unroll
    for (int e = 0; e < 4; ++e) {
        int s = lhi * 4 + e;
        int m = (s & 7) << 4;
        {
            float a = h2p0[e];
            float g = 1.f / (1.f + __expf(-a));
            *(__bf16*)(buf1 + ((s * 64 + l15 * 2) ^ m)) = (__bf16)(w3c0 * g * fmaf(a, 1.f - g, 1.f));
        }
        {
            float a = h2p1[e];
            float g = 1.f / (1.f + __expf(-a));
            *(__bf16*)(buf1 + ((s * 64 + (l15 + 16) * 2) ^ m)) = (__bf16)(w3c1 * g * fmaf(a, 1.f - g, 1.f));
        }
    }
    bf16x8 d2a = *(const bf16x8*)(buf1 + ((l15 * 64 + lhi * 16) ^ ((l15 & 7) << 4)));

    // ---- backward: u1 = d2 @ W2 ; d1 = u1 * t1 -> LDS transpose ----
    f32x4 z = {0.f, 0.f, 0.f, 0.f};
    f32x4 u10 = __builtin_amdgcn_mfma_f32_16x16x32_bf16(d2a, bw2b0, z, 0, 0, 0);
    f32x4 u11 = __builtin_amdgcn_mfma_f32_16x16x32_bf16(d2a, bw2b1, z, 0, 0, 0);
#pragma unroll
    for (int e = 0; e < 4; ++e) {
        int s = lhi * 4 + e;
        int m = (s & 7) << 4;
        *(__bf16*)(buf2 + ((s * 64 + l15 * 2) ^ m))        = (__bf16)(u10[e] * t10[e]);
        *(__bf16*)(buf2 + ((s * 64 + (l15 + 16) * 2) ^ m)) = (__bf16)(u11[e] * t11[e]);
    }
    bf16x8 d1a = *(const bf16x8*)(buf2 + ((l15 * 64 + lhi * 16) ^ ((l15 & 7) << 4)));

    // ---- output: gxp = d1 @ Wcp (swap+sign folded); out = x + DT*gxp ----
    f32x4 gx = __builtin_amdgcn_mfma_f32_16x16x32_bf16(d1a, bwc, z, 0, 0, 0);

    if (l15 < 6) {
#pragma unroll
        for (int e = 0; e < 4; ++e) {
            int di = (lhi * 4 + e) * 6 + l15;           // dword index in tile
            float xv = *(const float*)(xbuf + di * 4);
            *(float*)(obuf + di * 4) = fmaf(DT_STEP, gx[e], xv);
        }
    }
    // 1 coalesced store
    if (lane < 48)
        ((float2*)out)[(size_t)tile * 48 + lane] = *(const float2*)(obuf + lane * 8);
}

extern "C" void kernel_launch(void* const* d_in, const int* in_sizes, int n_in,
                              void* d_out, int out_size, void* d_ws, size_t ws_size,
                              hipStream_t stream) {
    const float* x    = (const float*)d_in[0];
    const float* W_in = (const float*)d_in[1];
    const float* b_in = (const float*)d_in[2];
    const float* W1   = (const float*)d_in[3];
    const float* b1   = (const float*)d_in[4];
    const float* W2   = (const float*)d_in[5];
    const float* b2   = (const float*)d_in[6];
    const float* W3   = (const float*)d_in[7];
    float* out = (float*)d_out;
    char* ws = (char*)d_ws;

    const int NS     = in_sizes[0] / 6;   // 131072 samples
    const int ntiles = NS / 16;           // 8192

    hvnn_setup<<<1, 256, 0, stream>>>(W_in, b_in, W1, b1, W2, b2, W3, ws);
    hvnn_mfma<<<(ntiles + 3) / 4, 256, 0, stream>>>(x, ws, out, ntiles);
}

// Round 5
// 16.653 us; speedup vs baseline: 1.9462x; 1.0875x over previous
//
#include <hip/hip_runtime.h>
#include <hip/hip_bf16.h>

#define DT_STEP 0.01f

typedef __bf16 bf16x8 __attribute__((ext_vector_type(8)));
typedef float  f32x4  __attribute__((ext_vector_type(4)));

// ---- LDS layout (bytes) ----
#define OFF_W2   0      // f32[1024]  W2 full
#define OFF_W1   4096   // f32[256]   W1 full
#define OFF_WIND 5120   // f32[48]    Win[d*256+i*32] as [d][i]
#define OFF_BIND 5312   // f32[8]     b_in diag
#define OFF_B1D  5344   // f32[32]    b1 diag
#define OFF_B2D  5472   // f32[32]    b2 diag
#define OFF_W3   5600   // f32[32]
#define OFF_WE   5728   // f32[6][32]  fold: embed@W1
#define OFF_BE   6496   // f32[32]     fold: bias
#define OFF_WCP  6624   // f32[32][8]  fold: bwd-embed + Hamiltonian swap/sign
#define OFF_WAVE 7680   // + wv*3072: bufA(1024) bufB(1024) xA(512) xB(512)
#define LDS_TOTAL (7680 + 4*3072)

__device__ __forceinline__ bf16x8 readT(const char* buf, int l15, int lhi) {
    return *(const bf16x8*)(buf + ((l15 * 64 + lhi * 16) ^ ((l15 & 7) << 4)));
}

// act1: h1 = a*sig(a) -> swizzled LDS; t = g*(1+a*(1-g)) kept in regs
__device__ __forceinline__ void act_sw(const f32x4& p0, const f32x4& p1,
                                       float* t0, float* t1, char* buf, int l15, int lhi) {
#pragma unroll
    for (int e = 0; e < 4; ++e) {
        int s = lhi * 4 + e, m = (s & 7) << 4;
        float a = p0[e], g = 1.f / (1.f + __expf(-a));
        t0[e] = g * fmaf(a, 1.f - g, 1.f);
        *(__bf16*)(buf + ((s * 64 + l15 * 2) ^ m)) = (__bf16)(a * g);
        a = p1[e]; g = 1.f / (1.f + __expf(-a));
        t1[e] = g * fmaf(a, 1.f - g, 1.f);
        *(__bf16*)(buf + ((s * 64 + (l15 + 16) * 2) ^ m)) = (__bf16)(a * g);
    }
}

// d2 = W3*g*(1+a*(1-g)) -> swizzled LDS
__device__ __forceinline__ void d2_sw(const f32x4& p0, const f32x4& p1,
                                      float w30, float w31, char* buf, int l15, int lhi) {
#pragma unroll
    for (int e = 0; e < 4; ++e) {
        int s = lhi * 4 + e, m = (s & 7) << 4;
        float a = p0[e], g = 1.f / (1.f + __expf(-a));
        *(__bf16*)(buf + ((s * 64 + l15 * 2) ^ m)) = (__bf16)(w30 * g * fmaf(a, 1.f - g, 1.f));
        a = p1[e]; g = 1.f / (1.f + __expf(-a));
        *(__bf16*)(buf + ((s * 64 + (l15 + 16) * 2) ^ m)) = (__bf16)(w31 * g * fmaf(a, 1.f - g, 1.f));
    }
}

// d1 = u1*t1 -> swizzled LDS
__device__ __forceinline__ void d1_sw(const f32x4& u0, const f32x4& u1,
                                      const float* t0, const float* t1, char* buf, int l15, int lhi) {
#pragma unroll
    for (int e = 0; e < 4; ++e) {
        int s = lhi * 4 + e, m = (s & 7) << 4;
        *(__bf16*)(buf + ((s * 64 + l15 * 2) ^ m))        = (__bf16)(u0[e] * t0[e]);
        *(__bf16*)(buf + ((s * 64 + (l15 + 16) * 2) ^ m)) = (__bf16)(u1[e] * t1[e]);
    }
}

// ---------------------------------------------------------------------------
// Single fused kernel. Per block: cooperative weight stage + fold, then each
// of 4 waves runs TWO phase-interleaved 16-sample MFMA chains (ILP-2).
// ---------------------------------------------------------------------------
__global__ __launch_bounds__(256) void hvnn_fused(
    const float* __restrict__ x,
    const float* __restrict__ Win, const float* __restrict__ bin,
    const float* __restrict__ W1,  const float* __restrict__ b1,
    const float* __restrict__ W2,  const float* __restrict__ b2,
    const float* __restrict__ W3,
    float* __restrict__ out, int ntiles)
{
    __shared__ __align__(16) char lds[LDS_TOTAL];
    const int tid = threadIdx.x;
    const int lane = tid & 63, wv = tid >> 6;
    const int l15 = lane & 15, lhi = lane >> 4;

    const int tileA = blockIdx.x * 8 + wv;
    const int tileB = tileA + 4;
    const bool vA = tileA < ntiles, vB = tileB < ntiles;

    char* wbase = lds + OFF_WAVE + wv * 3072;
    char* bufA = wbase;         char* bufB = wbase + 1024;
    char* xA   = wbase + 2048;  char* xB   = wbase + 2560;

    // ---- early x prefetch (per-wave LDS region, independent of barriers) ----
    if (lane < 48) {
        if (vA) *(float2*)(xA + lane * 8) = ((const float2*)x)[(size_t)tileA * 48 + lane];
        if (vB) *(float2*)(xB + lane * 8) = ((const float2*)x)[(size_t)tileB * 48 + lane];
    }

    // ---- stage raw weights (coalesced) ----
    ((float4*)(lds + OFF_W2))[tid] = ((const float4*)W2)[tid];   // 1024 f32
    ((float*)(lds + OFF_W1))[tid]  = W1[tid];                    // 256 f32
    if (tid < 48) ((float*)(lds + OFF_WIND))[tid] = Win[(tid >> 3) * 256 + (tid & 7) * 32];
    if (tid < 8)  ((float*)(lds + OFF_BIND))[tid] = bin[tid * 32];
    if (tid < 32) ((float*)(lds + OFF_B1D))[tid]  = b1[tid * 32];
    if (tid < 32) ((float*)(lds + OFF_B2D))[tid]  = b2[tid * 32];
    if (tid < 32) ((float*)(lds + OFF_W3))[tid]   = W3[tid];
    __syncthreads();

    // ---- folds ----
    const float* W1s  = (const float*)(lds + OFF_W1);
    const float* Wind = (const float*)(lds + OFF_WIND);
    if (tid < 192) {
        int d = tid >> 5, o = tid & 31;
        float a = 0.f;
#pragma unroll
        for (int i = 0; i < 8; ++i) a = fmaf(Wind[d * 8 + i], W1s[o * 8 + i], a);
        ((float*)(lds + OFF_WE))[d * 32 + o] = a;
    }
    if (tid < 32) {
        float a = ((const float*)(lds + OFF_B1D))[tid];
#pragma unroll
        for (int i = 0; i < 8; ++i) a = fmaf(((const float*)(lds + OFF_BIND))[i], W1s[tid * 8 + i], a);
        ((float*)(lds + OFF_BE))[tid] = a;
    }
    {
        int o = tid >> 3, d = tid & 7;
        float v = 0.f;
        if (d < 6) {
            int dd = d < 3 ? d + 3 : d - 3;
            float sg = d < 3 ? 1.f : -1.f;
            float a = 0.f;
#pragma unroll
            for (int i = 0; i < 8; ++i) a = fmaf(W1s[o * 8 + i], Wind[dd * 8 + i], a);
            v = sg * a;
        }
        ((float*)(lds + OFF_WCP))[o * 8 + d] = v;
    }
    __syncthreads();

    // ---- per-wave fragment assembly from LDS ----
    const float* WeS  = (const float*)(lds + OFF_WE);
    const float* W2s  = (const float*)(lds + OFF_W2);
    const float* WcpS = (const float*)(lds + OFF_WCP);
    bf16x8 bwe0 = {}, bwe1 = {}, bw2t0, bw2t1, bw2b0, bw2b1, bwc = {};
    if (lane < 16) {
#pragma unroll
        for (int d = 0; d < 6; ++d) {
            bwe0[d] = (__bf16)WeS[d * 32 + l15];
            bwe1[d] = (__bf16)WeS[d * 32 + l15 + 16];
        }
    }
#pragma unroll
    for (int j = 0; j < 8; ++j) {
        bw2t0[j] = (__bf16)W2s[l15 * 32 + lhi * 8 + j];
        bw2t1[j] = (__bf16)W2s[(l15 + 16) * 32 + lhi * 8 + j];
        bw2b0[j] = (__bf16)W2s[(lhi * 8 + j) * 32 + l15];
        bw2b1[j] = (__bf16)W2s[(lhi * 8 + j) * 32 + l15 + 16];
    }
    if (l15 < 6) {
#pragma unroll
        for (int j = 0; j < 8; ++j) bwc[j] = (__bf16)WcpS[(lhi * 8 + j) * 8 + l15];
    }
    const float be0  = ((const float*)(lds + OFF_BE))[l15];
    const float be1  = ((const float*)(lds + OFF_BE))[l15 + 16];
    const float b2c0 = ((const float*)(lds + OFF_B2D))[l15];
    const float b2c1 = ((const float*)(lds + OFF_B2D))[l15 + 16];
    const float w3c0 = ((const float*)(lds + OFF_W3))[l15];
    const float w3c1 = ((const float*)(lds + OFF_W3))[l15 + 16];

    // ---- two interleaved chains (A/B) ----
    bf16x8 axA = {}, axB = {};
    if (lane < 16) {
        const float* ra = (const float*)(xA + lane * 24);
        const float* rb = (const float*)(xB + lane * 24);
#pragma unroll
        for (int d = 0; d < 6; ++d) { axA[d] = (__bf16)ra[d]; axB[d] = (__bf16)rb[d]; }
    }

    const f32x4 c0 = {be0, be0, be0, be0}, c1 = {be1, be1, be1, be1};
    f32x4 h1p0A = __builtin_amdgcn_mfma_f32_16x16x32_bf16(axA, bwe0, c0, 0, 0, 0);
    f32x4 h1p1A = __builtin_amdgcn_mfma_f32_16x16x32_bf16(axA, bwe1, c1, 0, 0, 0);
    f32x4 h1p0B = __builtin_amdgcn_mfma_f32_16x16x32_bf16(axB, bwe0, c0, 0, 0, 0);
    f32x4 h1p1B = __builtin_amdgcn_mfma_f32_16x16x32_bf16(axB, bwe1, c1, 0, 0, 0);

    float t10A[4], t11A[4], t10B[4], t11B[4];
    act_sw(h1p0A, h1p1A, t10A, t11A, bufA, l15, lhi);
    act_sw(h1p0B, h1p1B, t10B, t11B, bufB, l15, lhi);
    bf16x8 h1aA = readT(bufA, l15, lhi);
    bf16x8 h1aB = readT(bufB, l15, lhi);

    const f32x4 cb0 = {b2c0, b2c0, b2c0, b2c0}, cb1 = {b2c1, b2c1, b2c1, b2c1};
    f32x4 h2p0A = __builtin_amdgcn_mfma_f32_16x16x32_bf16(h1aA, bw2t0, cb0, 0, 0, 0);
    f32x4 h2p1A = __builtin_amdgcn_mfma_f32_16x16x32_bf16(h1aA, bw2t1, cb1, 0, 0, 0);
    f32x4 h2p0B = __builtin_amdgcn_mfma_f32_16x16x32_bf16(h1aB, bw2t0, cb0, 0, 0, 0);
    f32x4 h2p1B = __builtin_amdgcn_mfma_f32_16x16x32_bf16(h1aB, bw2t1, cb1, 0, 0, 0);

    d2_sw(h2p0A, h2p1A, w3c0, w3c1, bufA, l15, lhi);
    d2_sw(h2p0B, h2p1B, w3c0, w3c1, bufB, l15, lhi);
    bf16x8 d2aA = readT(bufA, l15, lhi);
    bf16x8 d2aB = readT(bufB, l15, lhi);

    const f32x4 z = {0.f, 0.f, 0.f, 0.f};
    f32x4 u10A = __builtin_amdgcn_mfma_f32_16x16x32_bf16(d2aA, bw2b0, z, 0, 0, 0);
    f32x4 u11A = __builtin_amdgcn_mfma_f32_16x16x32_bf16(d2aA, bw2b1, z, 0, 0, 0);
    f32x4 u10B = __builtin_amdgcn_mfma_f32_16x16x32_bf16(d2aB, bw2b0, z, 0, 0, 0);
    f32x4 u11B = __builtin_amdgcn_mfma_f32_16x16x32_bf16(d2aB, bw2b1, z, 0, 0, 0);

    d1_sw(u10A, u11A, t10A, t11A, bufA, l15, lhi);
    d1_sw(u10B, u11B, t10B, t11B, bufB, l15, lhi);
    bf16x8 d1aA = readT(bufA, l15, lhi);
    bf16x8 d1aB = readT(bufB, l15, lhi);

    f32x4 gxA = __builtin_amdgcn_mfma_f32_16x16x32_bf16(d1aA, bwc, z, 0, 0, 0);
    f32x4 gxB = __builtin_amdgcn_mfma_f32_16x16x32_bf16(d1aB, bwc, z, 0, 0, 0);

    // epilogue: out = x + DT*gx, staged through buf (reused) for coalesced store
    if (l15 < 6) {
#pragma unroll
        for (int e = 0; e < 4; ++e) {
            int di = (lhi * 4 + e) * 6 + l15;
            *(float*)(bufA + di * 4) = fmaf(DT_STEP, gxA[e], *(const float*)(xA + di * 4));
            *(float*)(bufB + di * 4) = fmaf(DT_STEP, gxB[e], *(const float*)(xB + di * 4));
        }
    }
    if (lane < 48) {
        if (vA) ((float2*)out)[(size_t)tileA * 48 + lane] = *(const float2*)(bufA + lane * 8);
        if (vB) ((float2*)out)[(size_t)tileB * 48 + lane] = *(const float2*)(bufB + lane * 8);
    }
}

extern "C" void kernel_launch(void* const* d_in, const int* in_sizes, int n_in,
                              void* d_out, int out_size, void* d_ws, size_t ws_size,
                              hipStream_t stream) {
    const float* x    = (const float*)d_in[0];
    const float* W_in = (const float*)d_in[1];
    const float* b_in = (const float*)d_in[2];
    const float* W1   = (const float*)d_in[3];
    const float* b1   = (const float*)d_in[4];
    const float* W2   = (const float*)d_in[5];
    const float* b2   = (const float*)d_in[6];
    const float* W3   = (const float*)d_in[7];
    float* out = (float*)d_out;

    const int NS     = in_sizes[0] / 6;   // 131072 samples
    const int ntiles = NS / 16;           // 8192
    const int blocks = (ntiles + 7) / 8;  // 8 tiles per block (4 waves x 2)

    hvnn_fused<<<blocks, 256, 0, stream>>>(x, W_in, b_in, W1, b1, W2, b2, W3, out, ntiles);
}

// Round 6
// 15.383 us; speedup vs baseline: 2.1069x; 1.0825x over previous
//
#include <hip/hip_runtime.h>
#include <hip/hip_bf16.h>

#define DT_STEP 0.01f

typedef __bf16 bf16x8 __attribute__((ext_vector_type(8)));
typedef float  f32x4  __attribute__((ext_vector_type(4)));

// ---- LDS layout (bytes) ----
#define OFF_W2   0      // f32[1024]  W2 raw
#define OFF_W1   4096   // f32[256]   W1 raw
#define OFF_WIND 5120   // f32[6][8]  Win[d*256+i*32]
#define OFF_BIND 5312   // f32[8]
#define OFF_B1D  5344   // f32[32]
#define OFF_B2D  5472   // f32[32]
#define OFF_W3   5600   // f32[32]
#define OFF_WE   5728   // f32[6][32]  fold: embed@W1
#define OFF_BE   6496   // f32[32]
#define OFF_WCP  6624   // f32[32][8]  fold: DT * bwd-embed + swap/sign
#define OFF_WAVE 7680   // + wv*768: obufA(384) obufB(384)
#define LDS_TOTAL (7680 + 4*768)

// All GEMMs transposed: A = weights (rows permuted c1/c2), B = state
// (k=channel, n=sample=l15), D = next state (col=sample, row=channel).
// Row permutation c1(r)=(r>>2)*8+(r&3), c2=c1+4 makes lane (l15,lhi)'s
// D-pair hold channels {lhi*8+e} u {lhi*8+4+e} == exactly the B k-chunk
// lhi*8..+7 it must supply next -> in-register cvt/pack, no transposes.
__global__ __launch_bounds__(256) void hvnn_fused(
    const float* __restrict__ x,
    const float* __restrict__ Win, const float* __restrict__ bin,
    const float* __restrict__ W1,  const float* __restrict__ b1,
    const float* __restrict__ W2,  const float* __restrict__ b2,
    const float* __restrict__ W3,
    float* __restrict__ out, int ntiles)
{
    __shared__ __align__(16) char lds[LDS_TOTAL];
    const int tid = threadIdx.x;
    const int lane = tid & 63, wv = tid >> 6;
    const int l15 = lane & 15, lhi = lane >> 4;
    const int wid = blockIdx.x * 4 + wv;
    const int nwaves = gridDim.x * 4;

    // ---- stage raw weights (coalesced) ----
    ((float4*)(lds + OFF_W2))[tid] = ((const float4*)W2)[tid];
    ((float*)(lds + OFF_W1))[tid]  = W1[tid];
    if (tid < 48) ((float*)(lds + OFF_WIND))[tid] = Win[(tid >> 3) * 256 + (tid & 7) * 32];
    if (tid < 8)  ((float*)(lds + OFF_BIND))[tid] = bin[tid * 32];
    if (tid < 32) ((float*)(lds + OFF_B1D))[tid]  = b1[tid * 32];
    if (tid < 32) ((float*)(lds + OFF_B2D))[tid]  = b2[tid * 32];
    if (tid < 32) ((float*)(lds + OFF_W3))[tid]   = W3[tid];
    __syncthreads();

    // ---- folds ----
    const float* W1s  = (const float*)(lds + OFF_W1);
    const float* Wind = (const float*)(lds + OFF_WIND);
    if (tid < 192) {
        int d = tid >> 5, o = tid & 31;
        float a = 0.f;
#pragma unroll
        for (int i = 0; i < 8; ++i) a = fmaf(Wind[d * 8 + i], W1s[o * 8 + i], a);
        ((float*)(lds + OFF_WE))[d * 32 + o] = a;
    }
    if (tid < 32) {
        float a = ((const float*)(lds + OFF_B1D))[tid];
#pragma unroll
        for (int i = 0; i < 8; ++i) a = fmaf(((const float*)(lds + OFF_BIND))[i], W1s[tid * 8 + i], a);
        ((float*)(lds + OFF_BE))[tid] = a;
    }
    {
        int o = tid >> 3, d = tid & 7;
        float v = 0.f;
        if (d < 6) {
            int dd = d < 3 ? d + 3 : d - 3;
            float sg = d < 3 ? DT_STEP : -DT_STEP;   // DT folded here
            float a = 0.f;
#pragma unroll
            for (int i = 0; i < 8; ++i) a = fmaf(W1s[o * 8 + i], Wind[dd * 8 + i], a);
            v = sg * a;
        }
        ((float*)(lds + OFF_WCP))[o * 8 + d] = v;
    }
    __syncthreads();

    // ---- per-wave A-fragment + bias assembly (once, amortized 4 tiles) ----
    const float* WeS  = (const float*)(lds + OFF_WE);
    const float* W2s  = (const float*)(lds + OFF_W2);
    const float* WcpS = (const float*)(lds + OFF_WCP);
    const float* beS  = (const float*)(lds + OFF_BE);
    const float* b2dS = (const float*)(lds + OFF_B2D);
    const float* w3S  = (const float*)(lds + OFF_W3);
    const int c1 = ((l15 >> 2) << 3) | (l15 & 3);
    const int c2 = c1 + 4;

    bf16x8 awe1 = {}, awe2 = {};
    if (lhi == 0) {
#pragma unroll
        for (int d = 0; d < 6; ++d) {
            awe1[d] = (__bf16)WeS[d * 32 + c1];
            awe2[d] = (__bf16)WeS[d * 32 + c2];
        }
    }
    bf16x8 aw2f1, aw2f2, aw2b1, aw2b2;
#pragma unroll
    for (int j = 0; j < 8; ++j) {
        aw2f1[j] = (__bf16)W2s[c1 * 32 + lhi * 8 + j];
        aw2f2[j] = (__bf16)W2s[c2 * 32 + lhi * 8 + j];
        aw2b1[j] = (__bf16)W2s[(lhi * 8 + j) * 32 + c1];
        aw2b2[j] = (__bf16)W2s[(lhi * 8 + j) * 32 + c2];
    }
    bf16x8 awc = {};
    if (l15 < 6) {
#pragma unroll
        for (int j = 0; j < 8; ++j) awc[j] = (__bf16)WcpS[(lhi * 8 + j) * 8 + l15];
    }
    const f32x4 beC1 = *(const f32x4*)(beS + lhi * 8);
    const f32x4 beC2 = *(const f32x4*)(beS + lhi * 8 + 4);
    const f32x4 b2C1 = *(const f32x4*)(b2dS + lhi * 8);
    const f32x4 b2C2 = *(const f32x4*)(b2dS + lhi * 8 + 4);
    const f32x4 w3A  = *(const f32x4*)(w3S + lhi * 8);
    const f32x4 w3B  = *(const f32x4*)(w3S + lhi * 8 + 4);

    char* obufA = lds + OFF_WAVE + wv * 768;
    char* obufB = obufA + 384;
    const f32x4 z = {0.f, 0.f, 0.f, 0.f};

    // one dual-tile chain; x passed as per-lane regs (lanes lhi==0 hold
    // their sample's 6 floats as 3 float2)
    auto chain = [&](bool vA, bool vB, int tA, int tB,
                     float2 xa0, float2 xa1, float2 xa2,
                     float2 xb0, float2 xb1, float2 xb2) {
        bf16x8 bxA = {}, bxB = {};
        if (lhi == 0) {
            bxA[0] = (__bf16)xa0.x; bxA[1] = (__bf16)xa0.y; bxA[2] = (__bf16)xa1.x;
            bxA[3] = (__bf16)xa1.y; bxA[4] = (__bf16)xa2.x; bxA[5] = (__bf16)xa2.y;
            bxB[0] = (__bf16)xb0.x; bxB[1] = (__bf16)xb0.y; bxB[2] = (__bf16)xb1.x;
            bxB[3] = (__bf16)xb1.y; bxB[4] = (__bf16)xb2.x; bxB[5] = (__bf16)xb2.y;
        }
        // layer 1
        f32x4 h1A1 = __builtin_amdgcn_mfma_f32_16x16x32_bf16(awe1, bxA, beC1, 0, 0, 0);
        f32x4 h1A2 = __builtin_amdgcn_mfma_f32_16x16x32_bf16(awe2, bxA, beC2, 0, 0, 0);
        f32x4 h1B1 = __builtin_amdgcn_mfma_f32_16x16x32_bf16(awe1, bxB, beC1, 0, 0, 0);
        f32x4 h1B2 = __builtin_amdgcn_mfma_f32_16x16x32_bf16(awe2, bxB, beC2, 0, 0, 0);
        // act1 -> in-register B frag + t1 factors
        bf16x8 h1fA, h1fB; float t1A1[4], t1A2[4], t1B1[4], t1B2[4];
#pragma unroll
        for (int e = 0; e < 4; ++e) {
            float a, g;
            a = h1A1[e]; g = 1.f / (1.f + __expf(-a));
            t1A1[e] = g * fmaf(a, 1.f - g, 1.f); h1fA[e] = (__bf16)(a * g);
            a = h1A2[e]; g = 1.f / (1.f + __expf(-a));
            t1A2[e] = g * fmaf(a, 1.f - g, 1.f); h1fA[e + 4] = (__bf16)(a * g);
            a = h1B1[e]; g = 1.f / (1.f + __expf(-a));
            t1B1[e] = g * fmaf(a, 1.f - g, 1.f); h1fB[e] = (__bf16)(a * g);
            a = h1B2[e]; g = 1.f / (1.f + __expf(-a));
            t1B2[e] = g * fmaf(a, 1.f - g, 1.f); h1fB[e + 4] = (__bf16)(a * g);
        }
        // layer 2 fwd
        f32x4 h2A1 = __builtin_amdgcn_mfma_f32_16x16x32_bf16(aw2f1, h1fA, b2C1, 0, 0, 0);
        f32x4 h2A2 = __builtin_amdgcn_mfma_f32_16x16x32_bf16(aw2f2, h1fA, b2C2, 0, 0, 0);
        f32x4 h2B1 = __builtin_amdgcn_mfma_f32_16x16x32_bf16(aw2f1, h1fB, b2C1, 0, 0, 0);
        f32x4 h2B2 = __builtin_amdgcn_mfma_f32_16x16x32_bf16(aw2f2, h1fB, b2C2, 0, 0, 0);
        // d2 = W3*g*(1+a*(1-g)) -> B frag
        bf16x8 d2fA, d2fB;
#pragma unroll
        for (int e = 0; e < 4; ++e) {
            float a, g;
            a = h2A1[e]; g = 1.f / (1.f + __expf(-a));
            d2fA[e]     = (__bf16)(w3A[e] * g * fmaf(a, 1.f - g, 1.f));
            a = h2A2[e]; g = 1.f / (1.f + __expf(-a));
            d2fA[e + 4] = (__bf16)(w3B[e] * g * fmaf(a, 1.f - g, 1.f));
            a = h2B1[e]; g = 1.f / (1.f + __expf(-a));
            d2fB[e]     = (__bf16)(w3A[e] * g * fmaf(a, 1.f - g, 1.f));
            a = h2B2[e]; g = 1.f / (1.f + __expf(-a));
            d2fB[e + 4] = (__bf16)(w3B[e] * g * fmaf(a, 1.f - g, 1.f));
        }
        // backward u1 = W2^T @ d2
        f32x4 u1A1 = __builtin_amdgcn_mfma_f32_16x16x32_bf16(aw2b1, d2fA, z, 0, 0, 0);
        f32x4 u1A2 = __builtin_amdgcn_mfma_f32_16x16x32_bf16(aw2b2, d2fA, z, 0, 0, 0);
        f32x4 u1B1 = __builtin_amdgcn_mfma_f32_16x16x32_bf16(aw2b1, d2fB, z, 0, 0, 0);
        f32x4 u1B2 = __builtin_amdgcn_mfma_f32_16x16x32_bf16(aw2b2, d2fB, z, 0, 0, 0);
        // d1 = u1 * t1 -> B frag
        bf16x8 d1fA, d1fB;
#pragma unroll
        for (int e = 0; e < 4; ++e) {
            d1fA[e]     = (__bf16)(u1A1[e] * t1A1[e]);
            d1fA[e + 4] = (__bf16)(u1A2[e] * t1A2[e]);
            d1fB[e]     = (__bf16)(u1B1[e] * t1B1[e]);
            d1fB[e + 4] = (__bf16)(u1B2[e] * t1B2[e]);
        }
        // output GEMM (DT + Hamiltonian swap/sign folded into awc)
        f32x4 gxA = __builtin_amdgcn_mfma_f32_16x16x32_bf16(awc, d1fA, z, 0, 0, 0);
        f32x4 gxB = __builtin_amdgcn_mfma_f32_16x16x32_bf16(awc, d1fB, z, 0, 0, 0);

        // epilogue: gx -> per-wave LDS -> coalesced out = x + gx
        if (lhi < 2) {
#pragma unroll
            for (int e = 0; e < 4; ++e) {
                int d = lhi * 4 + e;
                if (d < 6) {
                    *(float*)(obufA + l15 * 24 + d * 4) = gxA[e];
                    *(float*)(obufB + l15 * 24 + d * 4) = gxB[e];
                }
            }
        }
        if (lane < 48) {
            if (vA) {
                float2 xv = ((const float2*)x)[(size_t)tA * 48 + lane];
                float2 g2 = *(const float2*)(obufA + lane * 8);
                ((float2*)out)[(size_t)tA * 48 + lane] = make_float2(xv.x + g2.x, xv.y + g2.y);
            }
            if (vB) {
                float2 xv = ((const float2*)x)[(size_t)tB * 48 + lane];
                float2 g2 = *(const float2*)(obufB + lane * 8);
                ((float2*)out)[(size_t)tB * 48 + lane] = make_float2(xv.x + g2.x, xv.y + g2.y);
            }
        }
    };

    // ---- 2 iterations x 2 tiles, x gathered to regs up front (prefetch) ----
    const int p0 = wid, p1 = nwaves + wid;
    const int tA0 = 2 * p0, tB0 = 2 * p0 + 1, tA1 = 2 * p1, tB1 = 2 * p1 + 1;
    const bool vA0 = tA0 < ntiles, vB0 = tB0 < ntiles;
    const bool vA1 = tA1 < ntiles, vB1 = tB1 < ntiles;

    float2 a00 = {}, a01 = {}, a02 = {}, b00 = {}, b01 = {}, b02 = {};
    float2 a10 = {}, a11 = {}, a12 = {}, b10 = {}, b11 = {}, b12 = {};
    if (lhi == 0) {
        const float2* xf2 = (const float2*)x;
        if (vA0) { const float2* p = xf2 + (size_t)tA0 * 48 + l15 * 3; a00 = p[0]; a01 = p[1]; a02 = p[2]; }
        if (vB0) { const float2* p = xf2 + (size_t)tB0 * 48 + l15 * 3; b00 = p[0]; b01 = p[1]; b02 = p[2]; }
        if (vA1) { const float2* p = xf2 + (size_t)tA1 * 48 + l15 * 3; a10 = p[0]; a11 = p[1]; a12 = p[2]; }
        if (vB1) { const float2* p = xf2 + (size_t)tB1 * 48 + l15 * 3; b10 = p[0]; b11 = p[1]; b12 = p[2]; }
    }
    chain(vA0, vB0, tA0, tB0, a00, a01, a02, b00, b01, b02);
    chain(vA1, vB1, tA1, tB1, a10, a11, a12, b10, b11, b12);
}

extern "C" void kernel_launch(void* const* d_in, const int* in_sizes, int n_in,
                              void* d_out, int out_size, void* d_ws, size_t ws_size,
                              hipStream_t stream) {
    const float* x    = (const float*)d_in[0];
    const float* W_in = (const float*)d_in[1];
    const float* b_in = (const float*)d_in[2];
    const float* W1   = (const float*)d_in[3];
    const float* b1   = (const float*)d_in[4];
    const float* W2   = (const float*)d_in[5];
    const float* b2   = (const float*)d_in[6];
    const float* W3   = (const float*)d_in[7];
    float* out = (float*)d_out;

    const int NS     = in_sizes[0] / 6;        // 131072 samples
    const int ntiles = (NS + 15) / 16;         // 8192
    const int blocks = (ntiles + 15) / 16;     // 16 tiles per block -> 512

    hvnn_fused<<<blocks, 256, 0, stream>>>(x, W_in, b_in, W1, b1, W2, b2, W3, out, ntiles);
}

// Round 7
// 13.723 us; speedup vs baseline: 2.3618x; 1.1210x over previous
//
#include <hip/hip_runtime.h>
#include <hip/hip_bf16.h>

#define DT_STEP 0.01f

typedef __bf16 bf16x8 __attribute__((ext_vector_type(8)));
typedef __bf16 bf16x4 __attribute__((ext_vector_type(4)));
typedef float  f32x4  __attribute__((ext_vector_type(4)));

// ---- LDS layout (bytes) ----
#define OFF_W2R  0      // bf16[32][32] row-major  (fwd fragments)
#define OFF_W2C  2048   // bf16[32][32] col-major  (bwd fragments)
#define OFF_W1   4096   // f32[256]   raw W1 (for folds)
#define OFF_WIND 5120   // f32[6][8]  Win diag cols (for folds)
#define OFF_BIND 5312   // f32[8]
#define OFF_B1D  5344   // f32[32]
#define OFF_B2D  5472   // f32[32]
#define OFF_W3   5600   // f32[32]
#define OFF_WE   5728   // f32[6][32]  fold: embed@W1
#define OFF_BE   6496   // f32[32]     fold: bias
#define OFF_WCPT 6624   // bf16[6][32] fold: DT*bwd-embed+swap/sign, TRANSPOSED
#define OFF_WAVE 7168   // + wv*768: obufA(384) obufB(384)
#define LDS_TOTAL (7168 + 4*768)

// All GEMMs transposed: A = weights (row-permuted c1/c2), B = state
// (k=channel, n=sample=l15). Permutation c1=(l15>>2)*8+(l15&3), c2=c1+4
// makes each lane's two D-quads hold exactly the B k-chunk lhi*8..+7 it
// feeds next -> whole chain stays in registers (no transposes).
__global__ __launch_bounds__(256) void hvnn_fused(
    const float* __restrict__ x,
    const float* __restrict__ Win, const float* __restrict__ bin,
    const float* __restrict__ W1,  const float* __restrict__ b1,
    const float* __restrict__ W2,  const float* __restrict__ b2,
    const float* __restrict__ W3,
    float* __restrict__ out, int ntiles)
{
    __shared__ __align__(16) char lds[LDS_TOTAL];
    const int tid = threadIdx.x;
    const int lane = tid & 63, wv = tid >> 6;
    const int l15 = lane & 15, lhi = lane >> 4;
    const int wid = blockIdx.x * 4 + wv;
    const int tA = wid * 2, tB = tA + 1;
    const bool vA = tA < ntiles, vB = tB < ntiles;

    // ---- x prefetch FIRST: latency hides under weight staging/folds ----
    float2 xa0 = {}, xa1 = {}, xa2 = {}, xb0 = {}, xb1 = {}, xb2 = {};
    float2 xsA = {}, xsB = {};
    if (lhi == 0) {
        const float2* xf2 = (const float2*)x;
        if (vA) { const float2* p = xf2 + (size_t)tA * 48 + l15 * 3; xa0 = p[0]; xa1 = p[1]; xa2 = p[2]; }
        if (vB) { const float2* p = xf2 + (size_t)tB * 48 + l15 * 3; xb0 = p[0]; xb1 = p[1]; xb2 = p[2]; }
    }
    if (lane < 48) {
        if (vA) xsA = ((const float2*)x)[(size_t)tA * 48 + lane];
        if (vB) xsB = ((const float2*)x)[(size_t)tB * 48 + lane];
    }

    // ---- stage raw weights; W2 converted to bf16 row- AND col-major ----
    {
        float4 w4 = ((const float4*)W2)[tid];         // row r, cols c0..c0+3
        int r = tid >> 3, c0 = (tid & 7) * 4;
        bf16x4 b4 = { (__bf16)w4.x, (__bf16)w4.y, (__bf16)w4.z, (__bf16)w4.w };
        *(bf16x4*)(lds + OFF_W2R + (r * 32 + c0) * 2) = b4;
        __bf16* col = (__bf16*)(lds + OFF_W2C);
        col[(c0 + 0) * 32 + r] = b4[0];
        col[(c0 + 1) * 32 + r] = b4[1];
        col[(c0 + 2) * 32 + r] = b4[2];
        col[(c0 + 3) * 32 + r] = b4[3];
    }
    ((float*)(lds + OFF_W1))[tid] = W1[tid];
    if (tid < 48) ((float*)(lds + OFF_WIND))[tid] = Win[(tid >> 3) * 256 + (tid & 7) * 32];
    if (tid < 8)  ((float*)(lds + OFF_BIND))[tid] = bin[tid * 32];
    if (tid < 32) ((float*)(lds + OFF_B1D))[tid]  = b1[tid * 32];
    if (tid < 32) ((float*)(lds + OFF_B2D))[tid]  = b2[tid * 32];
    if (tid < 32) ((float*)(lds + OFF_W3))[tid]   = W3[tid];
    __syncthreads();

    // ---- folds ----
    const float* W1s  = (const float*)(lds + OFF_W1);
    const float* Wind = (const float*)(lds + OFF_WIND);
    if (tid < 192) {
        int d = tid >> 5, o = tid & 31;
        float a = 0.f;
#pragma unroll
        for (int i = 0; i < 8; ++i) a = fmaf(Wind[d * 8 + i], W1s[o * 8 + i], a);
        ((float*)(lds + OFF_WE))[d * 32 + o] = a;
    }
    if (tid < 32) {
        float a = ((const float*)(lds + OFF_B1D))[tid];
#pragma unroll
        for (int i = 0; i < 8; ++i) a = fmaf(((const float*)(lds + OFF_BIND))[i], W1s[tid * 8 + i], a);
        ((float*)(lds + OFF_BE))[tid] = a;
    }
    {
        int o = tid >> 3, d = tid & 7;
        if (d < 6) {
            int dd = d < 3 ? d + 3 : d - 3;
            float sg = d < 3 ? DT_STEP : -DT_STEP;   // DT folded here
            float a = 0.f;
#pragma unroll
            for (int i = 0; i < 8; ++i) a = fmaf(W1s[o * 8 + i], Wind[dd * 8 + i], a);
            ((__bf16*)(lds + OFF_WCPT))[d * 32 + o] = (__bf16)(sg * a);  // transposed
        }
    }
    __syncthreads();

    // ---- fragment assembly: four ds_read_b128 for W2, one for Wcp ----
    const int c1 = ((l15 >> 2) << 3) | (l15 & 3);
    const int c2 = c1 + 4;
    const bf16x8 aw2f1 = *(const bf16x8*)(lds + OFF_W2R + (c1 * 32 + lhi * 8) * 2);
    const bf16x8 aw2f2 = *(const bf16x8*)(lds + OFF_W2R + (c2 * 32 + lhi * 8) * 2);
    const bf16x8 aw2b1 = *(const bf16x8*)(lds + OFF_W2C + (c1 * 32 + lhi * 8) * 2);
    const bf16x8 aw2b2 = *(const bf16x8*)(lds + OFF_W2C + (c2 * 32 + lhi * 8) * 2);
    bf16x8 awc = {};
    if (l15 < 6) awc = *(const bf16x8*)(lds + OFF_WCPT + l15 * 64 + lhi * 16);

    const float* WeS = (const float*)(lds + OFF_WE);
    bf16x8 awe1 = {}, awe2 = {};
    if (lhi == 0) {
#pragma unroll
        for (int d = 0; d < 6; ++d) {
            awe1[d] = (__bf16)WeS[d * 32 + c1];
            awe2[d] = (__bf16)WeS[d * 32 + c2];
        }
    }
    const f32x4 beC1 = *(const f32x4*)((const float*)(lds + OFF_BE) + lhi * 8);
    const f32x4 beC2 = *(const f32x4*)((const float*)(lds + OFF_BE) + lhi * 8 + 4);
    const f32x4 b2C1 = *(const f32x4*)((const float*)(lds + OFF_B2D) + lhi * 8);
    const f32x4 b2C2 = *(const f32x4*)((const float*)(lds + OFF_B2D) + lhi * 8 + 4);
    const f32x4 w3A  = *(const f32x4*)((const float*)(lds + OFF_W3) + lhi * 8);
    const f32x4 w3B  = *(const f32x4*)((const float*)(lds + OFF_W3) + lhi * 8 + 4);

    char* obufA = lds + OFF_WAVE + wv * 768;
    char* obufB = obufA + 384;
    const f32x4 z = {0.f, 0.f, 0.f, 0.f};

    // ---- B-fragments for x ----
    bf16x8 bxA = {}, bxB = {};
    if (lhi == 0) {
        bxA[0] = (__bf16)xa0.x; bxA[1] = (__bf16)xa0.y; bxA[2] = (__bf16)xa1.x;
        bxA[3] = (__bf16)xa1.y; bxA[4] = (__bf16)xa2.x; bxA[5] = (__bf16)xa2.y;
        bxB[0] = (__bf16)xb0.x; bxB[1] = (__bf16)xb0.y; bxB[2] = (__bf16)xb1.x;
        bxB[3] = (__bf16)xb1.y; bxB[4] = (__bf16)xb2.x; bxB[5] = (__bf16)xb2.y;
    }

    // ---- layer 1 ----
    f32x4 h1A1 = __builtin_amdgcn_mfma_f32_16x16x32_bf16(awe1, bxA, beC1, 0, 0, 0);
    f32x4 h1A2 = __builtin_amdgcn_mfma_f32_16x16x32_bf16(awe2, bxA, beC2, 0, 0, 0);
    f32x4 h1B1 = __builtin_amdgcn_mfma_f32_16x16x32_bf16(awe1, bxB, beC1, 0, 0, 0);
    f32x4 h1B2 = __builtin_amdgcn_mfma_f32_16x16x32_bf16(awe2, bxB, beC2, 0, 0, 0);

    bf16x8 h1fA, h1fB; float t1A1[4], t1A2[4], t1B1[4], t1B2[4];
#pragma unroll
    for (int e = 0; e < 4; ++e) {
        float a, g;
        a = h1A1[e]; g = 1.f / (1.f + __expf(-a));
        t1A1[e] = g * fmaf(a, 1.f - g, 1.f); h1fA[e] = (__bf16)(a * g);
        a = h1A2[e]; g = 1.f / (1.f + __expf(-a));
        t1A2[e] = g * fmaf(a, 1.f - g, 1.f); h1fA[e + 4] = (__bf16)(a * g);
        a = h1B1[e]; g = 1.f / (1.f + __expf(-a));
        t1B1[e] = g * fmaf(a, 1.f - g, 1.f); h1fB[e] = (__bf16)(a * g);
        a = h1B2[e]; g = 1.f / (1.f + __expf(-a));
        t1B2[e] = g * fmaf(a, 1.f - g, 1.f); h1fB[e + 4] = (__bf16)(a * g);
    }

    // ---- layer 2 fwd ----
    f32x4 h2A1 = __builtin_amdgcn_mfma_f32_16x16x32_bf16(aw2f1, h1fA, b2C1, 0, 0, 0);
    f32x4 h2A2 = __builtin_amdgcn_mfma_f32_16x16x32_bf16(aw2f2, h1fA, b2C2, 0, 0, 0);
    f32x4 h2B1 = __builtin_amdgcn_mfma_f32_16x16x32_bf16(aw2f1, h1fB, b2C1, 0, 0, 0);
    f32x4 h2B2 = __builtin_amdgcn_mfma_f32_16x16x32_bf16(aw2f2, h1fB, b2C2, 0, 0, 0);

    bf16x8 d2fA, d2fB;
#pragma unroll
    for (int e = 0; e < 4; ++e) {
        float a, g;
        a = h2A1[e]; g = 1.f / (1.f + __expf(-a));
        d2fA[e]     = (__bf16)(w3A[e] * g * fmaf(a, 1.f - g, 1.f));
        a = h2A2[e]; g = 1.f / (1.f + __expf(-a));
        d2fA[e + 4] = (__bf16)(w3B[e] * g * fmaf(a, 1.f - g, 1.f));
        a = h2B1[e]; g = 1.f / (1.f + __expf(-a));
        d2fB[e]     = (__bf16)(w3A[e] * g * fmaf(a, 1.f - g, 1.f));
        a = h2B2[e]; g = 1.f / (1.f + __expf(-a));
        d2fB[e + 4] = (__bf16)(w3B[e] * g * fmaf(a, 1.f - g, 1.f));
    }

    // ---- backward ----
    f32x4 u1A1 = __builtin_amdgcn_mfma_f32_16x16x32_bf16(aw2b1, d2fA, z, 0, 0, 0);
    f32x4 u1A2 = __builtin_amdgcn_mfma_f32_16x16x32_bf16(aw2b2, d2fA, z, 0, 0, 0);
    f32x4 u1B1 = __builtin_amdgcn_mfma_f32_16x16x32_bf16(aw2b1, d2fB, z, 0, 0, 0);
    f32x4 u1B2 = __builtin_amdgcn_mfma_f32_16x16x32_bf16(aw2b2, d2fB, z, 0, 0, 0);

    bf16x8 d1fA, d1fB;
#pragma unroll
    for (int e = 0; e < 4; ++e) {
        d1fA[e]     = (__bf16)(u1A1[e] * t1A1[e]);
        d1fA[e + 4] = (__bf16)(u1A2[e] * t1A2[e]);
        d1fB[e]     = (__bf16)(u1B1[e] * t1B1[e]);
        d1fB[e + 4] = (__bf16)(u1B2[e] * t1B2[e]);
    }

    // ---- output GEMM (DT + Hamiltonian swap/sign already in awc) ----
    f32x4 gxA = __builtin_amdgcn_mfma_f32_16x16x32_bf16(awc, d1fA, z, 0, 0, 0);
    f32x4 gxB = __builtin_amdgcn_mfma_f32_16x16x32_bf16(awc, d1fB, z, 0, 0, 0);

    // ---- epilogue: gx -> per-wave LDS -> coalesced out = x + gx ----
    if (lhi < 2) {
#pragma unroll
        for (int e = 0; e < 4; ++e) {
            int d = lhi * 4 + e;
            if (d < 6) {
                *(float*)(obufA + l15 * 24 + d * 4) = gxA[e];
                *(float*)(obufB + l15 * 24 + d * 4) = gxB[e];
            }
        }
    }
    if (lane < 48) {
        if (vA) {
            float2 g2 = *(const float2*)(obufA + lane * 8);
            ((float2*)out)[(size_t)tA * 48 + lane] = make_float2(xsA.x + g2.x, xsA.y + g2.y);
        }
        if (vB) {
            float2 g2 = *(const float2*)(obufB + lane * 8);
            ((float2*)out)[(size_t)tB * 48 + lane] = make_float2(xsB.x + g2.x, xsB.y + g2.y);
        }
    }
}

extern "C" void kernel_launch(void* const* d_in, const int* in_sizes, int n_in,
                              void* d_out, int out_size, void* d_ws, size_t ws_size,
                              hipStream_t stream) {
    const float* x    = (const float*)d_in[0];
    const float* W_in = (const float*)d_in[1];
    const float* b_in = (const float*)d_in[2];
    const float* W1   = (const float*)d_in[3];
    const float* b1   = (const float*)d_in[4];
    const float* W2   = (const float*)d_in[5];
    const float* b2   = (const float*)d_in[6];
    const float* W3   = (const float*)d_in[7];
    float* out = (float*)d_out;

    const int NS     = in_sizes[0] / 6;      // 131072 samples
    const int ntiles = (NS + 15) / 16;       // 8192
    const int blocks = (ntiles + 7) / 8;     // 2 tiles/wave, 4 waves -> 1024

    hvnn_fused<<<blocks, 256, 0, stream>>>(x, W_in, b_in, W1, b1, W2, b2, W3, out, ntiles);
}

// Round 8
// 13.485 us; speedup vs baseline: 2.4034x; 1.0176x over previous
//
#include <hip/hip_runtime.h>
#include <hip/hip_bf16.h>

#define DT_STEP 0.01f

typedef __bf16 bf16x8 __attribute__((ext_vector_type(8)));
typedef __bf16 bf16x4 __attribute__((ext_vector_type(4)));
typedef float  f32x4  __attribute__((ext_vector_type(4)));

// ---- LDS layout (bytes) ----
#define OFF_W2R  0      // bf16[32][32] row-major  (fwd fragments)
#define OFF_W2C  2048   // bf16[32][32] col-major  (bwd fragments)
#define OFF_W1   4096   // f32[256]   raw W1 (for folds)
#define OFF_WIND 5120   // f32[6][8]  Win diag cols (for folds)
#define OFF_BIND 5312   // f32[8]
#define OFF_B1D  5344   // f32[32]
#define OFF_B2D  5472   // f32[32]
#define OFF_W3   5600   // f32[32]
#define OFF_WE   5728   // f32[6][32]  fold: embed@W1
#define OFF_BE   6496   // f32[32]     fold: bias
#define OFF_WCPT 6624   // bf16[6][32] fold: DT*bwd-embed+swap/sign, TRANSPOSED
#define OFF_WAVE 7168   // + wv*768: obufA(384) obufB(384)
#define LDS_TOTAL (7168 + 4*768)

// All GEMMs transposed: A = weights (row-permuted c1/c2), B = state
// (k=channel, n=sample=l15). Permutation c1=(l15>>2)*8+(l15&3), c2=c1+4
// makes each lane's two D-quads hold exactly the B k-chunk lhi*8..+7 it
// feeds next -> whole chain stays in registers (no transposes).
// Final MFMA: C operand carries x (out = x + DT*grad done by the MFMA).
__global__ __launch_bounds__(256) void hvnn_fused(
    const float* __restrict__ x,
    const float* __restrict__ Win, const float* __restrict__ bin,
    const float* __restrict__ W1,  const float* __restrict__ b1,
    const float* __restrict__ W2,  const float* __restrict__ b2,
    const float* __restrict__ W3,
    float* __restrict__ out, int ntiles)
{
    __shared__ __align__(16) char lds[LDS_TOTAL];
    const int tid = threadIdx.x;
    const int lane = tid & 63, wv = tid >> 6;
    const int l15 = lane & 15, lhi = lane >> 4;
    const int wid = blockIdx.x * 4 + wv;
    const int tA = wid * 2, tB = tA + 1;
    const bool vA = tA < ntiles, vB = tB < ntiles;

    // ---- x prefetch FIRST (lhi<2: sample gather for B frag + final-C) ----
    float2 xa0 = {}, xa1 = {}, xa2 = {}, xb0 = {}, xb1 = {}, xb2 = {};
    if (lhi < 2) {
        const float2* xf2 = (const float2*)x;
        if (vA) { const float2* p = xf2 + (size_t)tA * 48 + l15 * 3; xa0 = p[0]; xa1 = p[1]; xa2 = p[2]; }
        if (vB) { const float2* p = xf2 + (size_t)tB * 48 + l15 * 3; xb0 = p[0]; xb1 = p[1]; xb2 = p[2]; }
    }

    // ---- stage raw weights; W2 converted to bf16 row- AND col-major ----
    {
        float4 w4 = ((const float4*)W2)[tid];         // row r, cols c0..c0+3
        int r = tid >> 3, c0 = (tid & 7) * 4;
        bf16x4 b4 = { (__bf16)w4.x, (__bf16)w4.y, (__bf16)w4.z, (__bf16)w4.w };
        *(bf16x4*)(lds + OFF_W2R + (r * 32 + c0) * 2) = b4;
        __bf16* col = (__bf16*)(lds + OFF_W2C);
        col[(c0 + 0) * 32 + r] = b4[0];
        col[(c0 + 1) * 32 + r] = b4[1];
        col[(c0 + 2) * 32 + r] = b4[2];
        col[(c0 + 3) * 32 + r] = b4[3];
    }
    ((float*)(lds + OFF_W1))[tid] = W1[tid];
    if (tid < 48) ((float*)(lds + OFF_WIND))[tid] = Win[(tid >> 3) * 256 + (tid & 7) * 32];
    if (tid < 8)  ((float*)(lds + OFF_BIND))[tid] = bin[tid * 32];
    if (tid < 32) ((float*)(lds + OFF_B1D))[tid]  = b1[tid * 32];
    if (tid < 32) ((float*)(lds + OFF_B2D))[tid]  = b2[tid * 32];
    if (tid < 32) ((float*)(lds + OFF_W3))[tid]   = W3[tid];
    __syncthreads();

    // ---- folds ----
    const float* W1s  = (const float*)(lds + OFF_W1);
    const float* Wind = (const float*)(lds + OFF_WIND);
    if (tid < 192) {
        int d = tid >> 5, o = tid & 31;
        float a = 0.f;
#pragma unroll
        for (int i = 0; i < 8; ++i) a = fmaf(Wind[d * 8 + i], W1s[o * 8 + i], a);
        ((float*)(lds + OFF_WE))[d * 32 + o] = a;
    }
    if (tid < 32) {
        float a = ((const float*)(lds + OFF_B1D))[tid];
#pragma unroll
        for (int i = 0; i < 8; ++i) a = fmaf(((const float*)(lds + OFF_BIND))[i], W1s[tid * 8 + i], a);
        ((float*)(lds + OFF_BE))[tid] = a;
    }
    {
        int o = tid >> 3, d = tid & 7;
        if (d < 6) {
            int dd = d < 3 ? d + 3 : d - 3;
            float sg = d < 3 ? DT_STEP : -DT_STEP;   // DT folded here
            float a = 0.f;
#pragma unroll
            for (int i = 0; i < 8; ++i) a = fmaf(W1s[o * 8 + i], Wind[dd * 8 + i], a);
            ((__bf16*)(lds + OFF_WCPT))[d * 32 + o] = (__bf16)(sg * a);  // transposed
        }
    }
    __syncthreads();

    // ---- fragment assembly: ds_read_b128s for W2 / Wcp ----
    const int c1 = ((l15 >> 2) << 3) | (l15 & 3);
    const int c2 = c1 + 4;
    const bf16x8 aw2f1 = *(const bf16x8*)(lds + OFF_W2R + (c1 * 32 + lhi * 8) * 2);
    const bf16x8 aw2f2 = *(const bf16x8*)(lds + OFF_W2R + (c2 * 32 + lhi * 8) * 2);
    const bf16x8 aw2b1 = *(const bf16x8*)(lds + OFF_W2C + (c1 * 32 + lhi * 8) * 2);
    const bf16x8 aw2b2 = *(const bf16x8*)(lds + OFF_W2C + (c2 * 32 + lhi * 8) * 2);
    bf16x8 awc = {};
    if (l15 < 6) awc = *(const bf16x8*)(lds + OFF_WCPT + l15 * 64 + lhi * 16);

    const float* WeS = (const float*)(lds + OFF_WE);
    bf16x8 awe1 = {}, awe2 = {};
    if (lhi == 0) {
#pragma unroll
        for (int d = 0; d < 6; ++d) {
            awe1[d] = (__bf16)WeS[d * 32 + c1];
            awe2[d] = (__bf16)WeS[d * 32 + c2];
        }
    }
    const f32x4 beC1 = *(const f32x4*)((const float*)(lds + OFF_BE) + lhi * 8);
    const f32x4 beC2 = *(const f32x4*)((const float*)(lds + OFF_BE) + lhi * 8 + 4);
    const f32x4 b2C1 = *(const f32x4*)((const float*)(lds + OFF_B2D) + lhi * 8);
    const f32x4 b2C2 = *(const f32x4*)((const float*)(lds + OFF_B2D) + lhi * 8 + 4);
    const f32x4 w3A  = *(const f32x4*)((const float*)(lds + OFF_W3) + lhi * 8);
    const f32x4 w3B  = *(const f32x4*)((const float*)(lds + OFF_W3) + lhi * 8 + 4);

    char* obufA = lds + OFF_WAVE + wv * 768;
    char* obufB = obufA + 384;
    const f32x4 z = {0.f, 0.f, 0.f, 0.f};

    // ---- B-fragments for x (lhi==0 lanes carry k=0..5) ----
    bf16x8 bxA = {}, bxB = {};
    if (lhi == 0) {
        bxA[0] = (__bf16)xa0.x; bxA[1] = (__bf16)xa0.y; bxA[2] = (__bf16)xa1.x;
        bxA[3] = (__bf16)xa1.y; bxA[4] = (__bf16)xa2.x; bxA[5] = (__bf16)xa2.y;
        bxB[0] = (__bf16)xb0.x; bxB[1] = (__bf16)xb0.y; bxB[2] = (__bf16)xb1.x;
        bxB[3] = (__bf16)xb1.y; bxB[4] = (__bf16)xb2.x; bxB[5] = (__bf16)xb2.y;
    }

    // ---- final-MFMA C operand = x (rows d=lhi*4+e, col=sample=l15) ----
    f32x4 cxA = z, cxB = z;
    if (lhi == 0) {
        cxA[0] = xa0.x; cxA[1] = xa0.y; cxA[2] = xa1.x; cxA[3] = xa1.y;
        cxB[0] = xb0.x; cxB[1] = xb0.y; cxB[2] = xb1.x; cxB[3] = xb1.y;
    } else if (lhi == 1) {
        cxA[0] = xa2.x; cxA[1] = xa2.y;
        cxB[0] = xb2.x; cxB[1] = xb2.y;
    }

    // ---- layer 1 ----
    f32x4 h1A1 = __builtin_amdgcn_mfma_f32_16x16x32_bf16(awe1, bxA, beC1, 0, 0, 0);
    f32x4 h1A2 = __builtin_amdgcn_mfma_f32_16x16x32_bf16(awe2, bxA, beC2, 0, 0, 0);
    f32x4 h1B1 = __builtin_amdgcn_mfma_f32_16x16x32_bf16(awe1, bxB, beC1, 0, 0, 0);
    f32x4 h1B2 = __builtin_amdgcn_mfma_f32_16x16x32_bf16(awe2, bxB, beC2, 0, 0, 0);

    bf16x8 h1fA, h1fB; float t1A1[4], t1A2[4], t1B1[4], t1B2[4];
#pragma unroll
    for (int e = 0; e < 4; ++e) {
        float a, g;
        a = h1A1[e]; g = 1.f / (1.f + __expf(-a));
        t1A1[e] = g * fmaf(a, 1.f - g, 1.f); h1fA[e] = (__bf16)(a * g);
        a = h1A2[e]; g = 1.f / (1.f + __expf(-a));
        t1A2[e] = g * fmaf(a, 1.f - g, 1.f); h1fA[e + 4] = (__bf16)(a * g);
        a = h1B1[e]; g = 1.f / (1.f + __expf(-a));
        t1B1[e] = g * fmaf(a, 1.f - g, 1.f); h1fB[e] = (__bf16)(a * g);
        a = h1B2[e]; g = 1.f / (1.f + __expf(-a));
        t1B2[e] = g * fmaf(a, 1.f - g, 1.f); h1fB[e + 4] = (__bf16)(a * g);
    }

    // ---- layer 2 fwd ----
    f32x4 h2A1 = __builtin_amdgcn_mfma_f32_16x16x32_bf16(aw2f1, h1fA, b2C1, 0, 0, 0);
    f32x4 h2A2 = __builtin_amdgcn_mfma_f32_16x16x32_bf16(aw2f2, h1fA, b2C2, 0, 0, 0);
    f32x4 h2B1 = __builtin_amdgcn_mfma_f32_16x16x32_bf16(aw2f1, h1fB, b2C1, 0, 0, 0);
    f32x4 h2B2 = __builtin_amdgcn_mfma_f32_16x16x32_bf16(aw2f2, h1fB, b2C2, 0, 0, 0);

    bf16x8 d2fA, d2fB;
#pragma unroll
    for (int e = 0; e < 4; ++e) {
        float a, g;
        a = h2A1[e]; g = 1.f / (1.f + __expf(-a));
        d2fA[e]     = (__bf16)(w3A[e] * g * fmaf(a, 1.f - g, 1.f));
        a = h2A2[e]; g = 1.f / (1.f + __expf(-a));
        d2fA[e + 4] = (__bf16)(w3B[e] * g * fmaf(a, 1.f - g, 1.f));
        a = h2B1[e]; g = 1.f / (1.f + __expf(-a));
        d2fB[e]     = (__bf16)(w3A[e] * g * fmaf(a, 1.f - g, 1.f));
        a = h2B2[e]; g = 1.f / (1.f + __expf(-a));
        d2fB[e + 4] = (__bf16)(w3B[e] * g * fmaf(a, 1.f - g, 1.f));
    }

    // ---- backward ----
    f32x4 u1A1 = __builtin_amdgcn_mfma_f32_16x16x32_bf16(aw2b1, d2fA, z, 0, 0, 0);
    f32x4 u1A2 = __builtin_amdgcn_mfma_f32_16x16x32_bf16(aw2b2, d2fA, z, 0, 0, 0);
    f32x4 u1B1 = __builtin_amdgcn_mfma_f32_16x16x32_bf16(aw2b1, d2fB, z, 0, 0, 0);
    f32x4 u1B2 = __builtin_amdgcn_mfma_f32_16x16x32_bf16(aw2b2, d2fB, z, 0, 0, 0);

    bf16x8 d1fA, d1fB;
#pragma unroll
    for (int e = 0; e < 4; ++e) {
        d1fA[e]     = (__bf16)(u1A1[e] * t1A1[e]);
        d1fA[e + 4] = (__bf16)(u1A2[e] * t1A2[e]);
        d1fB[e]     = (__bf16)(u1B1[e] * t1B1[e]);
        d1fB[e + 4] = (__bf16)(u1B2[e] * t1B2[e]);
    }

    // ---- output GEMM: D = Wcp@d1 + x  (DT, swap, sign, and +x all folded) ----
    f32x4 oA = __builtin_amdgcn_mfma_f32_16x16x32_bf16(awc, d1fA, cxA, 0, 0, 0);
    f32x4 oB = __builtin_amdgcn_mfma_f32_16x16x32_bf16(awc, d1fB, cxB, 0, 0, 0);

    // ---- epilogue: D -> per-wave LDS (float2-packed) -> coalesced store ----
    if (lhi == 0) {
        *(float2*)(obufA + l15 * 24)     = make_float2(oA[0], oA[1]);
        *(float2*)(obufA + l15 * 24 + 8) = make_float2(oA[2], oA[3]);
        *(float2*)(obufB + l15 * 24)     = make_float2(oB[0], oB[1]);
        *(float2*)(obufB + l15 * 24 + 8) = make_float2(oB[2], oB[3]);
    } else if (lhi == 1) {
        *(float2*)(obufA + l15 * 24 + 16) = make_float2(oA[0], oA[1]);
        *(float2*)(obufB + l15 * 24 + 16) = make_float2(oB[0], oB[1]);
    }
    if (lane < 48) {
        if (vA) ((float2*)out)[(size_t)tA * 48 + lane] = *(const float2*)(obufA + lane * 8);
        if (vB) ((float2*)out)[(size_t)tB * 48 + lane] = *(const float2*)(obufB + lane * 8);
    }
}

extern "C" void kernel_launch(void* const* d_in, const int* in_sizes, int n_in,
                              void* d_out, int out_size, void* d_ws, size_t ws_size,
                              hipStream_t stream) {
    const float* x    = (const float*)d_in[0];
    const float* W_in = (const float*)d_in[1];
    const float* b_in = (const float*)d_in[2];
    const float* W1   = (const float*)d_in[3];
    const float* b1   = (const float*)d_in[4];
    const float* W2   = (const float*)d_in[5];
    const float* b2   = (const float*)d_in[6];
    const float* W3   = (const float*)d_in[7];
    float* out = (float*)d_out;

    const int NS     = in_sizes[0] / 6;      // 131072 samples
    const int ntiles = (NS + 15) / 16;       // 8192
    const int blocks = (ntiles + 7) / 8;     // 2 tiles/wave, 4 waves -> 1024

    hvnn_fused<<<blocks, 256, 0, stream>>>(x, W_in, b_in, W1, b1, W2, b2, W3, out, ntiles);
}